// Round 4
// baseline (110.631 us; speedup 1.0000x reference)
//
#include <hip/hip_runtime.h>

typedef unsigned int u32;
typedef float f4 __attribute__((ext_vector_type(4)));

// Only the low 16 bits of every hash product matter (final % 65536, XOR is
// bitwise, mul distributes over mod 2^16) -> masked primes + __umul24.
__device__ constexpr u32 BASEP[16] = {
    2654435761u, 2246822519u, 3266489917u, 2028178513u,
    1220703125u, 1610612741u,  805306457u,  402653189u,
    3674653429u, 2860486313u, 1073676287u, 2971215073u,
    1500450271u, 3267000013u, 2654435789u, 4049292737u};
__device__ constexpr u32 EXTP[16] = {   // EXT32[16..31]
    2246822531u, 3266489927u, 2028178519u, 1220703133u,
    1610612759u,  805306463u,  402653201u, 3674653441u,
    2860486319u, 1073676311u, 2971215091u, 1500450277u,
    3267000023u, 2654435801u, 4049292751u, 2246822537u};

#define TDIM 4096
#define PPB  16          // positions per 256-thread block (16 lanes/position)
#define HALO 128

// Thread = (p = tid>>4, r = tid&15); r doubles as (s = r>>2, q = r&3):
// scale s, float4 q of the 64B table row. Hash terms split 16 ways
// (i = r + 16m); reductions use reduce-scatter (5 + 8 shuffles) and a
// ballot-based cond-key (0 shuffles) instead of full butterflies.
__global__ __launch_bounds__(256) void rhp_fused(
        const int* __restrict__ tokens, const float* __restrict__ tables,
        const float* __restrict__ Wc, float* __restrict__ out)
{
    __shared__ u32   toks[HALO + PPB];   // 144 tokens (halo zero-padded)
    __shared__ float wc_s[512];          // 8 x 64
    __shared__ u32   bp16[16], ep16[16]; // masked primes

    const int tid = threadIdx.x;
    const int g0  = blockIdx.x * PPB;        // flat position of tile start
    const int t0  = g0 & (TDIM - 1);         // 16 | 4096 -> no row straddle

    if (tid < 16) { bp16[tid] = BASEP[tid] & 0xFFFFu;
                    ep16[tid] = EXTP[tid]  & 0xFFFFu; }
    if (tid < 128) ((float4*)wc_s)[tid] = ((const float4*)Wc)[tid];
    if (tid < HALO + PPB) {
        const int t = t0 - HALO + tid;       // in-row index; <0 -> zero pad
        toks[tid] = (t >= 0) ? (u32)tokens[g0 - HALO + tid] : 0u;
    }
    __syncthreads();

    const int r   = tid & 15;
    const int p   = tid >> 4;
    const int pos = g0 + p;
    const int s   = (tid >> 2) & 3;
    const int q   = tid & 3;
    const int b3  = (r >> 3) & 1;
    const int b2  = (r >> 2) & 1;
    const int b1  = (r >> 1) & 1;

    // ---- hash partials: this thread covers term indices i = r + 16m ----
    const int base = HALO + p - 1 - r;       // min 0, max 142
    const u32 v0 = toks[base      ], v1 = toks[base -  16];
    const u32 v2 = toks[base -  32], v3 = toks[base -  48];
    const u32 v4 = toks[base -  64], v5 = toks[base -  80];
    const u32 v6 = toks[base -  96], v7 = toks[base - 112];

    const u32 pb  = bp16[r];                 // BASE[r] & 0xFFFF
    const u32 pb7 = bp16[r & 7];             // BASE[r&7] & 0xFFFF
    const u32 pe  = ep16[r];                 // EXT32[16+r] & 0xFFFF
    const u32 p7  = pb7 ^ 0xF00Du;           // ^0x8BADF00D (low 16)
    const u32 p6  = pb7 ^ 0xBABEu;           // ^0xCAFEBABE
    const u32 p5a = pb  ^ 0xBEEFu;           // ^0xDEADBEEF, i = r
    const u32 p5b = pe  ^ 0xBEEFu;           //              i = r+16

    u32 k7p = __umul24(v0, p7) ^ __umul24(v1, p7) ^ __umul24(v2, p7) ^
              __umul24(v3, p7) ^ __umul24(v4, p7) ^ __umul24(v5, p7) ^
              __umul24(v6, p7) ^ __umul24(v7, p7);
    u32 k6p = __umul24(v0, p6) ^ __umul24(v1, p6) ^
              __umul24(v2, p6) ^ __umul24(v3, p6);
    u32 k5p = __umul24(v0, p5a) ^ __umul24(v1, p5b);
    u32 k4p = __umul24(v0, pb);
    const u32 k3p = (r < 8) ? k4p : 0u;      // k0..k3 reuse k4's i=r term
    const u32 k2p = (r < 4) ? k4p : 0u;
    const u32 k1p = (r < 2) ? k4p : 0u;
    const u32 k0p = (r == 0) ? k4p : 0u;

    // pack short|long<<16 per scale-pair
    const u32 P0 = (k0p & 0xFFFFu) | ((k4p & 0xFFFFu) << 16);
    const u32 P1 = (k1p & 0xFFFFu) | ((k5p & 0xFFFFu) << 16);
    const u32 P2 = (k2p & 0xFFFFu) | ((k6p & 0xFFFFu) << 16);
    const u32 P3 = (k3p & 0xFFFFu) | ((k7p & 0xFFFFu) << 16);

    // ---- key reduce-scatter over the 16 lanes: 5 shuffles ----
    // lane ends with its own scale's key: s = (b3<<1)|b2
    u32 QA = b3 ? P2 : P0, RA = b3 ? P0 : P2;
    u32 QB = b3 ? P3 : P1, RB = b3 ? P1 : P3;
    QA ^= __shfl_xor(RA, 8);
    QB ^= __shfl_xor(RB, 8);
    u32 Q = b2 ? QB : QA, R = b2 ? QA : QB;
    Q ^= __shfl_xor(R, 4);
    Q ^= __shfl_xor(Q, 2);
    Q ^= __shfl_xor(Q, 1);
    const u32 Ps = Q;                        // packed k_s | k_{s+4}<<16
    const u32 ks = Ps & 0xFFFFu;

    // ---- short gather: quad-coalesced 64B row (4 lanes x float4) ----
    const f4 sv = *(const f4*)(tables + (u32)s * 1048576u
                               + ks * 16u + (u32)q * 4u);
    __builtin_nontemporal_store(
        sv, (f4*)(out + (size_t)pos * 128u + (u32)s * 16u + (u32)q * 4u));

    // ---- partial logits over this lane's 4 columns (c = s*16 + q*4 + u) ----
    float lg[8];
#pragma unroll
    for (int j = 0; j < 8; ++j) {
        const float4 w = ((const float4*)wc_s)[j * 16 + s * 4 + q];
        lg[j] = fmaf(sv.x, w.x, fmaf(sv.y, w.y, fmaf(sv.z, w.z, sv.w * w.w)));
    }

    // ---- logit reduce-scatter: 8 shuffles; lane ends with j = (r>>1)&7 ----
    float q0 = b3 ? lg[4] : lg[0], r0 = b3 ? lg[0] : lg[4];
    float q1 = b3 ? lg[5] : lg[1], r1 = b3 ? lg[1] : lg[5];
    float q2 = b3 ? lg[6] : lg[2], r2 = b3 ? lg[2] : lg[6];
    float q3 = b3 ? lg[7] : lg[3], r3 = b3 ? lg[3] : lg[7];
    q0 += __shfl_xor(r0, 8);
    q1 += __shfl_xor(r1, 8);
    q2 += __shfl_xor(r2, 8);
    q3 += __shfl_xor(r3, 8);
    float m0 = b2 ? q2 : q0, n0 = b2 ? q0 : q2;
    float m1 = b2 ? q3 : q1, n1 = b2 ? q1 : q3;
    m0 += __shfl_xor(n0, 4);
    m1 += __shfl_xor(n1, 4);
    float fin = b1 ? m1 : m0, fr = b1 ? m0 : m1;
    fin += __shfl_xor(fr, 2);
    fin += __shfl_xor(fin, 1);               // logit j, reduced over 16 lanes

    // ---- cond-key via ballot (no shuffles) ----
    // group g = lane>>4; lane g*16 + 2j (and +1) holds sign of logit j
    const unsigned long long bal = __ballot(fin > 0.0f);
    const u32 mg = (u32)(bal >> (tid & 48)) & 0xFFFFu;
    u32 ck = 0u;
#pragma unroll
    for (int j = 0; j < 8; ++j)
        if ((mg >> (2 * j)) & 1) ck ^= (BASEP[j] & 0xFFFFu);

    // ---- long gather: tables[s+4][(k_{s+4} ^ ck) % 65536] ----
    const u32 kl = ((Ps >> 16) ^ ck) & 0xFFFFu;
    const f4 lv = *(const f4*)(tables + (u32)(s + 4) * 1048576u
                               + kl * 16u + (u32)q * 4u);
    __builtin_nontemporal_store(
        lv, (f4*)(out + (size_t)pos * 128u + 64u + (u32)s * 16u + (u32)q * 4u));
}

extern "C" void kernel_launch(void* const* d_in, const int* in_sizes, int n_in,
                              void* d_out, int out_size, void* d_ws, size_t ws_size,
                              hipStream_t stream) {
    const int*   tokens = (const int*)d_in[0];
    const float* tables = (const float*)d_in[1];
    const float* Wc     = (const float*)d_in[2];
    float*       out    = (float*)d_out;

    const int n_pos = in_sizes[0];             // B*T = 131072
    hipLaunchKernelGGL(rhp_fused, dim3(n_pos / PPB), dim3(256), 0, stream,
                       tokens, tables, Wc, out);
}